// Round 10
// baseline (255.749 us; speedup 1.0000x reference)
//
#include <hip/hip_runtime.h>

typedef _Float16 f16x8 __attribute__((ext_vector_type(8)));
typedef _Float16 f16x4 __attribute__((ext_vector_type(4)));
typedef float    f32x4 __attribute__((ext_vector_type(4)));
typedef unsigned int u32x4 __attribute__((ext_vector_type(4)));

constexpr int NTOK   = 1568;       // T*H*W = 8*14*14
constexpr int NHEADS = 8;
constexpr int NCH    = 512;
constexpr int NC32   = 52;         // 32-token chunks, padded to 1664 tokens
constexpr float SK   = 0.15014030f; // 0.125*sqrt(log2 e): (q*SK)·(k*SK) = s*log2e/64 -> p = exp2(.)
constexpr size_t IMG_BH = (size_t)NC32 * 4096;   // 212992 B per (bh) per image

// ---- pre-pass: build fragment-major K and V images (every frag = contiguous 1KB, lane*16) ----
// K frag (c16 = tok/16, ks): slot(l15,grp,j) = x[tok=c16*16+l15][d=ks*32+8grp+j] * SK
// V frag (c32 = tok/32, db): slot(l15,grp,j) = x[tok=c32*32+16*(j>>2)+4grp+(j&3)][d=db*16+l15]
__global__ __launch_bounds__(256)
void prep_kernel(const float* __restrict__ x, char* __restrict__ Kimg, char* __restrict__ Vimg)
{
    const int bh = blockIdx.x, c32 = blockIdx.y;
    const int b = bh >> 3, h = bh & 7;
    const int t = threadIdx.x;
    const int f = t >> 6, l = t & 63, l15 = l & 15, grp = l >> 4;

    char* Kg = Kimg + (size_t)bh * IMG_BH + (size_t)(c32 * 4 + f) * 1024 + l * 16;
    char* Vg = Vimg + (size_t)bh * IMG_BH + (size_t)(c32 * 4 + f) * 1024 + l * 16;

    const int n0 = c32 * 32;
    if (n0 >= NTOK) {                       // pure padding chunk
        f16x8 z;
#pragma unroll
        for (int j = 0; j < 8; ++j) z[j] = (_Float16)0.f;
        *(f16x8*)Kg = z; *(f16x8*)Vg = z;
        return;
    }

    __shared__ _Float16 kbuf[32][72];       // [tok][d], scaled
    __shared__ _Float16 vbuf[64][40];       // [d][tok]

    const int tok = t & 31, dhi = t >> 5;   // coalesced: 8 x 128B segments per pass
#pragma unroll
    for (int p = 0; p < 8; ++p) {
        const int d = 8 * p + dhi;
        const float v = x[((size_t)b * NCH + d * NHEADS + h) * NTOK + n0 + tok];
        kbuf[tok][d] = (_Float16)(v * SK);
        vbuf[d][tok] = (_Float16)v;
    }
    __syncthreads();

    // K frag f: cb = f>>1 (16-tok half), ks = f&1
    *(f16x8*)Kg = *(const f16x8*)&kbuf[(f >> 1) * 16 + l15][(f & 1) * 32 + grp * 8];
    // V frag db = f: token quads {4grp..+3} and {16+4grp..+3}
    f16x4 va = *(const f16x4*)&vbuf[f * 16 + l15][4 * grp];
    f16x4 vb = *(const f16x4*)&vbuf[f * 16 + l15][16 + 4 * grp];
    f16x8 vv;
#pragma unroll
    for (int j = 0; j < 4; ++j) { vv[j] = va[j]; vv[4 + j] = vb[j]; }
    *(f16x8*)Vg = vv;
}

// pack 8 exp2(s) values into one P fragment — pure register ops, no union/memory
static __device__ __forceinline__ f16x8 make_bp(f32x4 sA, f32x4 sB)
{
    u32x4 w;
    w[0] = __builtin_bit_cast(unsigned int,
        __builtin_amdgcn_cvt_pkrtz(__builtin_amdgcn_exp2f(sA[0]), __builtin_amdgcn_exp2f(sA[1])));
    w[1] = __builtin_bit_cast(unsigned int,
        __builtin_amdgcn_cvt_pkrtz(__builtin_amdgcn_exp2f(sA[2]), __builtin_amdgcn_exp2f(sA[3])));
    w[2] = __builtin_bit_cast(unsigned int,
        __builtin_amdgcn_cvt_pkrtz(__builtin_amdgcn_exp2f(sB[0]), __builtin_amdgcn_exp2f(sB[1])));
    w[3] = __builtin_bit_cast(unsigned int,
        __builtin_amdgcn_cvt_pkrtz(__builtin_amdgcn_exp2f(sB[2]), __builtin_amdgcn_exp2f(sB[3])));
    return __builtin_bit_cast(f16x8, w);
}

// combine helpers: statically-indexed register arrays by reference (inlined -> stays in VGPRs)
static __device__ __forceinline__ void dump_part(float (*row)[69], int lane,
                                                 const f32x4 (&oacc)[4][4], const f32x4 (&lacc)[4])
{
#pragma unroll
    for (int s = 0; s < 4; ++s) {
#pragma unroll
        for (int db = 0; db < 4; ++db)
#pragma unroll
            for (int q = 0; q < 4; ++q) row[lane][s * 16 + db * 4 + q] = oacc[s][db][q];
        row[lane][64 + s] = lacc[s][0];
    }
}
static __device__ __forceinline__ void add_part(const float (*row)[69], int lane,
                                                f32x4 (&oacc)[4][4], f32x4 (&lacc)[4])
{
#pragma unroll
    for (int s = 0; s < 4; ++s) {
#pragma unroll
        for (int db = 0; db < 4; ++db)
#pragma unroll
            for (int q = 0; q < 4; ++q) oacc[s][db][q] += row[lane][s * 16 + db * 4 + q];
        lacc[s][0] += row[lane][64 + s];
    }
}

// ---- main attention: no LDS/barriers in hot loop, L2-direct coalesced frag loads, 8 waves ----
__global__ __launch_bounds__(512, 5)
void attn_fwd(const char* __restrict__ Kimg, const char* __restrict__ Vimg,
              float* __restrict__ out)
{
    // XCD-aware bijective remap (800 = 8*100): 4 bh per XCD -> both images L2-resident
    const int orig = blockIdx.x;
    const int wgid = (orig & 7) * 100 + (orig >> 3);
    const int qt = wgid % 25, bh = wgid / 25;
    const int b = bh >> 3, head = bh & 7;
    const int t = threadIdx.x, kw = t >> 6, lane = t & 63;
    const int l15 = lane & 15, grp = lane >> 4;

    const char* Kb = Kimg + (size_t)bh * IMG_BH;
    const char* Vb = Vimg + (size_t)bh * IMG_BH;

    // Q fragments: B operand (col = l15 = q-row), from the padded K image (scale baked in)
    f16x8 aq[4][2];
#pragma unroll
    for (int sub = 0; sub < 4; ++sub)
#pragma unroll
        for (int ks = 0; ks < 2; ++ks)
            aq[sub][ks] = *(const f16x8*)(Kb + (size_t)((qt * 4 + sub) * 2 + ks) * 1024 + lane * 16);

    f16x8 ones;
#pragma unroll
    for (int j = 0; j < 8; ++j) ones[j] = (_Float16)1.f;

    f32x4 oacc[4][4];
    f32x4 lacc[4];
#pragma unroll
    for (int s = 0; s < 4; ++s) {
        lacc[s] = f32x4{0.f, 0.f, 0.f, 0.f};
#pragma unroll
        for (int db = 0; db < 4; ++db) oacc[s][db] = f32x4{0.f, 0.f, 0.f, 0.f};
    }

    // 49 valid chunks split 7 + 6*7 across the 8 kw waves
    const int start = (kw == 0) ? 0 : 7 + (kw - 1) * 6;
    const int nc    = (kw == 0) ? 7 : 6;
    const f32x4 z4 = {0.f, 0.f, 0.f, 0.f};

    for (int i = 0; i < nc; ++i) {
        const int c32 = start + i;
        const char* kbase = Kb + (size_t)c32 * 4096 + lane * 16;
        const char* vbase = Vb + (size_t)c32 * 4096 + lane * 16;

        f16x8 ka0 = *(const f16x8*)(kbase);
        f16x8 ka1 = *(const f16x8*)(kbase + 1024);
        f16x8 kb0 = *(const f16x8*)(kbase + 2048);
        f16x8 kb1 = *(const f16x8*)(kbase + 3072);
        f16x8 vf0 = *(const f16x8*)(vbase);
        f16x8 vf1 = *(const f16x8*)(vbase + 1024);
        f16x8 vf2 = *(const f16x8*)(vbase + 2048);
        f16x8 vf3 = *(const f16x8*)(vbase + 3072);

        // per q-subgroup: S^T both 16-token halves -> pack P -> denominator + PV MFMAs
#pragma unroll
        for (int sub = 0; sub < 4; ++sub) {
            f32x4 sA = __builtin_amdgcn_mfma_f32_16x16x32_f16(ka0, aq[sub][0], z4, 0, 0, 0);
            sA = __builtin_amdgcn_mfma_f32_16x16x32_f16(ka1, aq[sub][1], sA, 0, 0, 0);
            f32x4 sB = __builtin_amdgcn_mfma_f32_16x16x32_f16(kb0, aq[sub][0], z4, 0, 0, 0);
            sB = __builtin_amdgcn_mfma_f32_16x16x32_f16(kb1, aq[sub][1], sB, 0, 0, 0);
            const f16x8 bp = make_bp(sA, sB);   // slot j = token 16*(j>>2)+4grp+(j&3)
            lacc[sub]    = __builtin_amdgcn_mfma_f32_16x16x32_f16(ones, bp, lacc[sub], 0, 0, 0);
            oacc[sub][0] = __builtin_amdgcn_mfma_f32_16x16x32_f16(vf0, bp, oacc[sub][0], 0, 0, 0);
            oacc[sub][1] = __builtin_amdgcn_mfma_f32_16x16x32_f16(vf1, bp, oacc[sub][1], 0, 0, 0);
            oacc[sub][2] = __builtin_amdgcn_mfma_f32_16x16x32_f16(vf2, bp, oacc[sub][2], 0, 0, 0);
            oacc[sub][3] = __builtin_amdgcn_mfma_f32_16x16x32_f16(vf3, bp, oacc[sub][3], 0, 0, 0);
        }
    }

    // ---- pairwise-tree combine of 8 wave partials (2 LDS buffers, conflict-free stride) ----
    __shared__ float comb[2][64][69];       // 35.3 KB; (69*lane)%32 spans all banks
    if (kw == 1) dump_part(comb[0], lane, oacc, lacc);
    if (kw == 5) dump_part(comb[1], lane, oacc, lacc);
    __syncthreads();
    if (kw == 0) add_part(comb[0], lane, oacc, lacc);
    if (kw == 4) add_part(comb[1], lane, oacc, lacc);
    __syncthreads();
    if (kw == 2) dump_part(comb[0], lane, oacc, lacc);
    if (kw == 6) dump_part(comb[1], lane, oacc, lacc);
    __syncthreads();
    if (kw == 0) add_part(comb[0], lane, oacc, lacc);
    if (kw == 4) add_part(comb[1], lane, oacc, lacc);
    __syncthreads();
    if (kw == 3) dump_part(comb[0], lane, oacc, lacc);
    if (kw == 7) dump_part(comb[1], lane, oacc, lacc);
    __syncthreads();
    if (kw == 0) add_part(comb[0], lane, oacc, lacc);
    if (kw == 4) add_part(comb[1], lane, oacc, lacc);
    __syncthreads();
    if (kw == 4) dump_part(comb[0], lane, oacc, lacc);
    __syncthreads();

    if (kw == 0) {
        add_part(comb[0], lane, oacc, lacc);
        // lacc[s][0] is the full denominator for column q = l15 (MFMA reduced all k in-instruction)
#pragma unroll
        for (int sub = 0; sub < 4; ++sub) {
            const int qrow = qt * 64 + sub * 16 + l15;
            if (qrow < NTOK) {
                const float inv = 1.0f / lacc[sub][0];
#pragma unroll
                for (int db = 0; db < 4; ++db)
#pragma unroll
                    for (int q = 0; q < 4; ++q) {
                        const int d = db * 16 + 4 * grp + q;   // O^T: row=d, col=q
                        out[((size_t)b * NCH + (size_t)d * NHEADS + head) * NTOK + qrow] = oacc[sub][db][q] * inv;
                    }
            }
        }
    }
}

extern "C" void kernel_launch(void* const* d_in, const int* in_sizes, int n_in,
                              void* d_out, int out_size, void* d_ws, size_t ws_size,
                              hipStream_t stream)
{
    const float* x = (const float*)d_in[0];
    float* out     = (float*)d_out;

    char* Kimg = (char*)d_ws;                       // 32 * 208KB = 6.8 MB
    char* Vimg = (char*)d_ws + 32 * IMG_BH;         // + 6.8 MB

    dim3 pgrid(32, NC32);                           // 32 bh x 52 chunks
    prep_kernel<<<pgrid, 256, 0, stream>>>(x, Kimg, Vimg);

    attn_fwd<<<800, 512, 0, stream>>>(Kimg, Vimg, out);   // 25 q-tiles x 32 bh, XCD-remapped
}

// Round 11
// 52.741 us; speedup vs baseline: 4.8491x; 4.8491x over previous
//
#include <hip/hip_runtime.h>

typedef _Float16 f16x8 __attribute__((ext_vector_type(8)));
typedef _Float16 f16x4 __attribute__((ext_vector_type(4)));
typedef float    f32x4 __attribute__((ext_vector_type(4)));
typedef unsigned int u32x4 __attribute__((ext_vector_type(4)));

constexpr int NTOK   = 1568;       // T*H*W = 8*14*14
constexpr int NHEADS = 8;
constexpr int NCH    = 512;
constexpr int NC32   = 52;         // 32-token chunks, padded to 1664 tokens
constexpr float SK   = 0.15014030f; // 0.125*sqrt(log2 e): (q*SK)·(k*SK) = s*log2e/64 -> p = exp2(.)
constexpr size_t IMG_BH = (size_t)NC32 * 4096;   // 212992 B per (bh) per image

// ---- pre-pass: build fragment-major K and V images (every frag = contiguous 1KB, lane*16) ----
// K frag (c16 = tok/16, ks): slot(l15,grp,j) = x[tok=c16*16+l15][d=ks*32+8grp+j] * SK
// V frag (c32 = tok/32, db): slot(l15,grp,j) = x[tok=c32*32+16*(j>>2)+4grp+(j&3)][d=db*16+l15]
__global__ __launch_bounds__(256)
void prep_kernel(const float* __restrict__ x, char* __restrict__ Kimg, char* __restrict__ Vimg)
{
    const int bh = blockIdx.x, c32 = blockIdx.y;
    const int b = bh >> 3, h = bh & 7;
    const int t = threadIdx.x;
    const int f = t >> 6, l = t & 63, l15 = l & 15, grp = l >> 4;

    char* Kg = Kimg + (size_t)bh * IMG_BH + (size_t)(c32 * 4 + f) * 1024 + l * 16;
    char* Vg = Vimg + (size_t)bh * IMG_BH + (size_t)(c32 * 4 + f) * 1024 + l * 16;

    const int n0 = c32 * 32;
    if (n0 >= NTOK) {                       // pure padding chunk
        f16x8 z;
#pragma unroll
        for (int j = 0; j < 8; ++j) z[j] = (_Float16)0.f;
        *(f16x8*)Kg = z; *(f16x8*)Vg = z;
        return;
    }

    __shared__ _Float16 kbuf[32][72];       // [tok][d], scaled
    __shared__ _Float16 vbuf[64][40];       // [d][tok]

    const int tok = t & 31, dhi = t >> 5;   // coalesced: 8 x 128B segments per pass
#pragma unroll
    for (int p = 0; p < 8; ++p) {
        const int d = 8 * p + dhi;
        const float v = x[((size_t)b * NCH + d * NHEADS + h) * NTOK + n0 + tok];
        kbuf[tok][d] = (_Float16)(v * SK);
        vbuf[d][tok] = (_Float16)v;
    }
    __syncthreads();

    // K frag f: cb = f>>1 (16-tok half), ks = f&1
    *(f16x8*)Kg = *(const f16x8*)&kbuf[(f >> 1) * 16 + l15][(f & 1) * 32 + grp * 8];
    // V frag db = f: token quads {4grp..+3} and {16+4grp..+3}
    f16x4 va = *(const f16x4*)&vbuf[f * 16 + l15][4 * grp];
    f16x4 vb = *(const f16x4*)&vbuf[f * 16 + l15][16 + 4 * grp];
    f16x8 vv;
#pragma unroll
    for (int j = 0; j < 4; ++j) { vv[j] = va[j]; vv[4 + j] = vb[j]; }
    *(f16x8*)Vg = vv;
}

// pack 8 exp2(s) values into one P fragment — pure register ops, no union/memory
static __device__ __forceinline__ f16x8 make_bp(f32x4 sA, f32x4 sB)
{
    u32x4 w;
    w[0] = __builtin_bit_cast(unsigned int,
        __builtin_amdgcn_cvt_pkrtz(__builtin_amdgcn_exp2f(sA[0]), __builtin_amdgcn_exp2f(sA[1])));
    w[1] = __builtin_bit_cast(unsigned int,
        __builtin_amdgcn_cvt_pkrtz(__builtin_amdgcn_exp2f(sA[2]), __builtin_amdgcn_exp2f(sA[3])));
    w[2] = __builtin_bit_cast(unsigned int,
        __builtin_amdgcn_cvt_pkrtz(__builtin_amdgcn_exp2f(sB[0]), __builtin_amdgcn_exp2f(sB[1])));
    w[3] = __builtin_bit_cast(unsigned int,
        __builtin_amdgcn_cvt_pkrtz(__builtin_amdgcn_exp2f(sB[2]), __builtin_amdgcn_exp2f(sB[3])));
    return __builtin_bit_cast(f16x8, w);
}

// combine helpers: statically-indexed register arrays by reference (inlined -> stays in VGPRs)
static __device__ __forceinline__ void dump_part(float (*row)[69], int lane,
                                                 const f32x4 (&oacc)[4][4], const f32x4 (&lacc)[4])
{
#pragma unroll
    for (int s = 0; s < 4; ++s) {
#pragma unroll
        for (int db = 0; db < 4; ++db)
#pragma unroll
            for (int q = 0; q < 4; ++q) row[lane][s * 16 + db * 4 + q] = oacc[s][db][q];
        row[lane][64 + s] = lacc[s][0];
    }
}
static __device__ __forceinline__ void add_part(const float (*row)[69], int lane,
                                                f32x4 (&oacc)[4][4], f32x4 (&lacc)[4])
{
#pragma unroll
    for (int s = 0; s < 4; ++s) {
#pragma unroll
        for (int db = 0; db < 4; ++db)
#pragma unroll
            for (int q = 0; q < 4; ++q) oacc[s][db][q] += row[lane][s * 16 + db * 4 + q];
        lacc[s][0] += row[lane][64 + s];
    }
}

// ---- main attention: no LDS/barriers in hot loop, L2-direct coalesced frag loads, 8 waves ----
// launch_bounds(512,3): VGPR cap ~170 (same effective cap as round 9's proven (256,3)).
// (512,5) forced VGPR 48 -> total accumulator spill, 250us. Occupancy comes from the grid, not the hint.
__global__ __launch_bounds__(512, 3)
void attn_fwd(const char* __restrict__ Kimg, const char* __restrict__ Vimg,
              float* __restrict__ out)
{
    // XCD-aware bijective remap (800 = 8*100): 4 bh per XCD -> both images L2-resident
    const int orig = blockIdx.x;
    const int wgid = (orig & 7) * 100 + (orig >> 3);
    const int qt = wgid % 25, bh = wgid / 25;
    const int b = bh >> 3, head = bh & 7;
    const int t = threadIdx.x, kw = t >> 6, lane = t & 63;
    const int l15 = lane & 15, grp = lane >> 4;

    const char* Kb = Kimg + (size_t)bh * IMG_BH;
    const char* Vb = Vimg + (size_t)bh * IMG_BH;

    // Q fragments: B operand (col = l15 = q-row), from the padded K image (scale baked in)
    f16x8 aq[4][2];
#pragma unroll
    for (int sub = 0; sub < 4; ++sub)
#pragma unroll
        for (int ks = 0; ks < 2; ++ks)
            aq[sub][ks] = *(const f16x8*)(Kb + (size_t)((qt * 4 + sub) * 2 + ks) * 1024 + lane * 16);

    f16x8 ones;
#pragma unroll
    for (int j = 0; j < 8; ++j) ones[j] = (_Float16)1.f;

    f32x4 oacc[4][4];
    f32x4 lacc[4];
#pragma unroll
    for (int s = 0; s < 4; ++s) {
        lacc[s] = f32x4{0.f, 0.f, 0.f, 0.f};
#pragma unroll
        for (int db = 0; db < 4; ++db) oacc[s][db] = f32x4{0.f, 0.f, 0.f, 0.f};
    }

    // 49 valid chunks split 7 + 6*7 across the 8 kw waves
    const int start = (kw == 0) ? 0 : 7 + (kw - 1) * 6;
    const int nc    = (kw == 0) ? 7 : 6;
    const f32x4 z4 = {0.f, 0.f, 0.f, 0.f};

    for (int i = 0; i < nc; ++i) {
        const int c32 = start + i;
        const char* kbase = Kb + (size_t)c32 * 4096 + lane * 16;
        const char* vbase = Vb + (size_t)c32 * 4096 + lane * 16;

        f16x8 ka0 = *(const f16x8*)(kbase);
        f16x8 ka1 = *(const f16x8*)(kbase + 1024);
        f16x8 kb0 = *(const f16x8*)(kbase + 2048);
        f16x8 kb1 = *(const f16x8*)(kbase + 3072);
        f16x8 vf0 = *(const f16x8*)(vbase);
        f16x8 vf1 = *(const f16x8*)(vbase + 1024);
        f16x8 vf2 = *(const f16x8*)(vbase + 2048);
        f16x8 vf3 = *(const f16x8*)(vbase + 3072);

        // per q-subgroup: S^T both 16-token halves -> pack P -> denominator + PV MFMAs
#pragma unroll
        for (int sub = 0; sub < 4; ++sub) {
            f32x4 sA = __builtin_amdgcn_mfma_f32_16x16x32_f16(ka0, aq[sub][0], z4, 0, 0, 0);
            sA = __builtin_amdgcn_mfma_f32_16x16x32_f16(ka1, aq[sub][1], sA, 0, 0, 0);
            f32x4 sB = __builtin_amdgcn_mfma_f32_16x16x32_f16(kb0, aq[sub][0], z4, 0, 0, 0);
            sB = __builtin_amdgcn_mfma_f32_16x16x32_f16(kb1, aq[sub][1], sB, 0, 0, 0);
            const f16x8 bp = make_bp(sA, sB);   // slot j = token 16*(j>>2)+4grp+(j&3)
            lacc[sub]    = __builtin_amdgcn_mfma_f32_16x16x32_f16(ones, bp, lacc[sub], 0, 0, 0);
            oacc[sub][0] = __builtin_amdgcn_mfma_f32_16x16x32_f16(vf0, bp, oacc[sub][0], 0, 0, 0);
            oacc[sub][1] = __builtin_amdgcn_mfma_f32_16x16x32_f16(vf1, bp, oacc[sub][1], 0, 0, 0);
            oacc[sub][2] = __builtin_amdgcn_mfma_f32_16x16x32_f16(vf2, bp, oacc[sub][2], 0, 0, 0);
            oacc[sub][3] = __builtin_amdgcn_mfma_f32_16x16x32_f16(vf3, bp, oacc[sub][3], 0, 0, 0);
        }
    }

    // ---- pairwise-tree combine of 8 wave partials (2 LDS buffers, conflict-free stride) ----
    __shared__ float comb[2][64][69];       // 35.3 KB; (69*lane)%32 spans all banks
    if (kw == 1) dump_part(comb[0], lane, oacc, lacc);
    if (kw == 5) dump_part(comb[1], lane, oacc, lacc);
    __syncthreads();
    if (kw == 0) add_part(comb[0], lane, oacc, lacc);
    if (kw == 4) add_part(comb[1], lane, oacc, lacc);
    __syncthreads();
    if (kw == 2) dump_part(comb[0], lane, oacc, lacc);
    if (kw == 6) dump_part(comb[1], lane, oacc, lacc);
    __syncthreads();
    if (kw == 0) add_part(comb[0], lane, oacc, lacc);
    if (kw == 4) add_part(comb[1], lane, oacc, lacc);
    __syncthreads();
    if (kw == 3) dump_part(comb[0], lane, oacc, lacc);
    if (kw == 7) dump_part(comb[1], lane, oacc, lacc);
    __syncthreads();
    if (kw == 0) add_part(comb[0], lane, oacc, lacc);
    if (kw == 4) add_part(comb[1], lane, oacc, lacc);
    __syncthreads();
    if (kw == 4) dump_part(comb[0], lane, oacc, lacc);
    __syncthreads();

    if (kw == 0) {
        add_part(comb[0], lane, oacc, lacc);
        // lacc[s][0] is the full denominator for column q = l15 (MFMA reduced all k in-instruction)
#pragma unroll
        for (int sub = 0; sub < 4; ++sub) {
            const int qrow = qt * 64 + sub * 16 + l15;
            if (qrow < NTOK) {
                const float inv = 1.0f / lacc[sub][0];
#pragma unroll
                for (int db = 0; db < 4; ++db)
#pragma unroll
                    for (int q = 0; q < 4; ++q) {
                        const int d = db * 16 + 4 * grp + q;   // O^T: row=d, col=q
                        out[((size_t)b * NCH + (size_t)d * NHEADS + head) * NTOK + qrow] = oacc[sub][db][q] * inv;
                    }
            }
        }
    }
}

extern "C" void kernel_launch(void* const* d_in, const int* in_sizes, int n_in,
                              void* d_out, int out_size, void* d_ws, size_t ws_size,
                              hipStream_t stream)
{
    const float* x = (const float*)d_in[0];
    float* out     = (float*)d_out;

    char* Kimg = (char*)d_ws;                       // 32 * 208KB = 6.8 MB
    char* Vimg = (char*)d_ws + 32 * IMG_BH;         // + 6.8 MB

    dim3 pgrid(32, NC32);                           // 32 bh x 52 chunks
    prep_kernel<<<pgrid, 256, 0, stream>>>(x, Kimg, Vimg);

    attn_fwd<<<800, 512, 0, stream>>>(Kimg, Vimg, out);   // 25 q-tiles x 32 bh, XCD-remapped
}

// Round 12
// 47.372 us; speedup vs baseline: 5.3987x; 1.1133x over previous
//
#include <hip/hip_runtime.h>

typedef _Float16 f16x8 __attribute__((ext_vector_type(8)));
typedef _Float16 f16x4 __attribute__((ext_vector_type(4)));
typedef float    f32x4 __attribute__((ext_vector_type(4)));
typedef unsigned int u32x4 __attribute__((ext_vector_type(4)));

constexpr int NTOK   = 1568;       // T*H*W = 8*14*14
constexpr int NHEADS = 8;
constexpr int NCH    = 512;
constexpr int NC32   = 52;         // 32-token chunks, padded to 1664 tokens
constexpr float SK   = 0.15014030f; // 0.125*sqrt(log2 e): (q*SK)·(k*SK) = s*log2e/64 -> p = exp2(.)
constexpr size_t IMG_BH = (size_t)NC32 * 4096;   // 212992 B per (bh) per image

// ---- pre-pass: build fragment-major K and V images (every frag = contiguous 1KB, lane*16) ----
// K frag (c16 = tok/16, ks): slot(l15,grp,j) = x[tok=c16*16+l15][d=ks*32+8grp+j] * SK
// V frag (c32 = tok/32, db): slot(l15,grp,j) = x[tok=c32*32+16*(j>>2)+4grp+(j&3)][d=db*16+l15]
__global__ __launch_bounds__(256)
void prep_kernel(const float* __restrict__ x, char* __restrict__ Kimg, char* __restrict__ Vimg)
{
    const int bh = blockIdx.x, c32 = blockIdx.y;
    const int b = bh >> 3, h = bh & 7;
    const int t = threadIdx.x;
    const int f = t >> 6, l = t & 63, l15 = l & 15, grp = l >> 4;

    char* Kg = Kimg + (size_t)bh * IMG_BH + (size_t)(c32 * 4 + f) * 1024 + l * 16;
    char* Vg = Vimg + (size_t)bh * IMG_BH + (size_t)(c32 * 4 + f) * 1024 + l * 16;

    const int n0 = c32 * 32;
    if (n0 >= NTOK) {                       // pure padding chunk
        f16x8 z;
#pragma unroll
        for (int j = 0; j < 8; ++j) z[j] = (_Float16)0.f;
        *(f16x8*)Kg = z; *(f16x8*)Vg = z;
        return;
    }

    __shared__ _Float16 kbuf[32][72];       // [tok][d], scaled
    __shared__ _Float16 vbuf[64][40];       // [d][tok]

    const int tok = t & 31, dhi = t >> 5;   // coalesced: 8 x 128B segments per pass
#pragma unroll
    for (int p = 0; p < 8; ++p) {
        const int d = 8 * p + dhi;
        const float v = x[((size_t)b * NCH + d * NHEADS + h) * NTOK + n0 + tok];
        kbuf[tok][d] = (_Float16)(v * SK);
        vbuf[d][tok] = (_Float16)v;
    }
    __syncthreads();

    // K frag f: cb = f>>1 (16-tok half), ks = f&1
    *(f16x8*)Kg = *(const f16x8*)&kbuf[(f >> 1) * 16 + l15][(f & 1) * 32 + grp * 8];
    // V frag db = f: token quads {4grp..+3} and {16+4grp..+3}
    f16x4 va = *(const f16x4*)&vbuf[f * 16 + l15][4 * grp];
    f16x4 vb = *(const f16x4*)&vbuf[f * 16 + l15][16 + 4 * grp];
    f16x8 vv;
#pragma unroll
    for (int j = 0; j < 4; ++j) { vv[j] = va[j]; vv[4 + j] = vb[j]; }
    *(f16x8*)Vg = vv;
}

// pack 8 exp2(s) values into one P fragment — pure register ops, no union/memory
static __device__ __forceinline__ f16x8 make_bp(f32x4 sA, f32x4 sB)
{
    u32x4 w;
    w[0] = __builtin_bit_cast(unsigned int,
        __builtin_amdgcn_cvt_pkrtz(__builtin_amdgcn_exp2f(sA[0]), __builtin_amdgcn_exp2f(sA[1])));
    w[1] = __builtin_bit_cast(unsigned int,
        __builtin_amdgcn_cvt_pkrtz(__builtin_amdgcn_exp2f(sA[2]), __builtin_amdgcn_exp2f(sA[3])));
    w[2] = __builtin_bit_cast(unsigned int,
        __builtin_amdgcn_cvt_pkrtz(__builtin_amdgcn_exp2f(sB[0]), __builtin_amdgcn_exp2f(sB[1])));
    w[3] = __builtin_bit_cast(unsigned int,
        __builtin_amdgcn_cvt_pkrtz(__builtin_amdgcn_exp2f(sB[2]), __builtin_amdgcn_exp2f(sB[3])));
    return __builtin_bit_cast(f16x8, w);
}

// combine helpers: statically-indexed register arrays by reference (inlined -> stays in VGPRs)
static __device__ __forceinline__ void dump_part(float (*row)[69], int lane,
                                                 const f32x4 (&oacc)[4][4], const f32x4 (&lacc)[4])
{
#pragma unroll
    for (int s = 0; s < 4; ++s) {
#pragma unroll
        for (int db = 0; db < 4; ++db)
#pragma unroll
            for (int q = 0; q < 4; ++q) row[lane][s * 16 + db * 4 + q] = oacc[s][db][q];
        row[lane][64 + s] = lacc[s][0];
    }
}
static __device__ __forceinline__ void add_part(const float (*row)[69], int lane,
                                                f32x4 (&oacc)[4][4], f32x4 (&lacc)[4])
{
#pragma unroll
    for (int s = 0; s < 4; ++s) {
#pragma unroll
        for (int db = 0; db < 4; ++db)
#pragma unroll
            for (int q = 0; q < 4; ++q) oacc[s][db][q] += row[lane][s * 16 + db * 4 + q];
        lacc[s][0] += row[lane][64 + s];
    }
}

// ---- main attention: 4 waves, no LDS/barriers in hot loop, staggered K/V prefetch ----
// Pipeline per chunk: QK(ck)->bp | ck dead: load K(i+1) | PV(cv,bp) hides K-latency |
// cv dead: load V(i+1); next chunk's QK+exp hides V-latency. Zero extra buffer registers.
__global__ __launch_bounds__(256, 3)
void attn_fwd(const char* __restrict__ Kimg, const char* __restrict__ Vimg,
              float* __restrict__ out)
{
    // XCD-aware bijective remap (800 = 8*100): 4 bh per XCD -> both images L2-resident
    const int orig = blockIdx.x;
    const int wgid = (orig & 7) * 100 + (orig >> 3);
    const int qt = wgid % 25, bh = wgid / 25;
    const int b = bh >> 3, head = bh & 7;
    const int t = threadIdx.x, kw = t >> 6, lane = t & 63;
    const int l15 = lane & 15, grp = lane >> 4;

    const char* Kb = Kimg + (size_t)bh * IMG_BH;
    const char* Vb = Vimg + (size_t)bh * IMG_BH;

    // Q fragments: B operand (col = l15 = q-row), from the padded K image (scale baked in)
    f16x8 aq[4][2];
#pragma unroll
    for (int sub = 0; sub < 4; ++sub)
#pragma unroll
        for (int ks = 0; ks < 2; ++ks)
            aq[sub][ks] = *(const f16x8*)(Kb + (size_t)((qt * 4 + sub) * 2 + ks) * 1024 + lane * 16);

    f16x8 ones;
#pragma unroll
    for (int j = 0; j < 8; ++j) ones[j] = (_Float16)1.f;

    f32x4 oacc[4][4];
    f32x4 lacc[4];
#pragma unroll
    for (int s = 0; s < 4; ++s) {
        lacc[s] = f32x4{0.f, 0.f, 0.f, 0.f};
#pragma unroll
        for (int db = 0; db < 4; ++db) oacc[s][db] = f32x4{0.f, 0.f, 0.f, 0.f};
    }

    // 49 valid chunks split 13/12/12/12 across the 4 kw waves
    const int start = (kw == 0) ? 0 : 13 + (kw - 1) * 12;
    const int nc    = (kw == 0) ? 13 : 12;
    const f32x4 z4 = {0.f, 0.f, 0.f, 0.f};

    // prologue: chunk `start` into registers
    f16x8 ck0, ck1, ck2, ck3, cv0, cv1, cv2, cv3;
    {
        const char* kb0 = Kb + (size_t)start * 4096 + lane * 16;
        const char* vb0 = Vb + (size_t)start * 4096 + lane * 16;
        ck0 = *(const f16x8*)(kb0);
        ck1 = *(const f16x8*)(kb0 + 1024);
        ck2 = *(const f16x8*)(kb0 + 2048);
        ck3 = *(const f16x8*)(kb0 + 3072);
        cv0 = *(const f16x8*)(vb0);
        cv1 = *(const f16x8*)(vb0 + 1024);
        cv2 = *(const f16x8*)(vb0 + 2048);
        cv3 = *(const f16x8*)(vb0 + 3072);
    }

    for (int i = 0; i < nc; ++i) {
        // next-chunk base: start+i+1 <= 49 < 52 always inside the zero-padded image
        const char* nkb = Kb + (size_t)(start + i + 1) * 4096 + lane * 16;
        const char* nvb = Vb + (size_t)(start + i + 1) * 4096 + lane * 16;

        // phase 1: S^T for all 4 q-subgroups -> P fragments (slot j = token 16*(j>>2)+4grp+(j&3))
        f16x8 bp[4];
#pragma unroll
        for (int sub = 0; sub < 4; ++sub) {
            f32x4 sA = __builtin_amdgcn_mfma_f32_16x16x32_f16(ck0, aq[sub][0], z4, 0, 0, 0);
            sA = __builtin_amdgcn_mfma_f32_16x16x32_f16(ck1, aq[sub][1], sA, 0, 0, 0);
            f32x4 sB = __builtin_amdgcn_mfma_f32_16x16x32_f16(ck2, aq[sub][0], z4, 0, 0, 0);
            sB = __builtin_amdgcn_mfma_f32_16x16x32_f16(ck3, aq[sub][1], sB, 0, 0, 0);
            bp[sub] = make_bp(sA, sB);
        }
        // phase 2: ck registers dead -> prefetch next chunk's K into them
        ck0 = *(const f16x8*)(nkb);
        ck1 = *(const f16x8*)(nkb + 1024);
        ck2 = *(const f16x8*)(nkb + 2048);
        ck3 = *(const f16x8*)(nkb + 3072);
        // phase 3: denominator + PV (20 MFMAs cover the K prefetch latency)
#pragma unroll
        for (int sub = 0; sub < 4; ++sub) {
            lacc[sub]    = __builtin_amdgcn_mfma_f32_16x16x32_f16(ones, bp[sub], lacc[sub], 0, 0, 0);
            oacc[sub][0] = __builtin_amdgcn_mfma_f32_16x16x32_f16(cv0, bp[sub], oacc[sub][0], 0, 0, 0);
            oacc[sub][1] = __builtin_amdgcn_mfma_f32_16x16x32_f16(cv1, bp[sub], oacc[sub][1], 0, 0, 0);
            oacc[sub][2] = __builtin_amdgcn_mfma_f32_16x16x32_f16(cv2, bp[sub], oacc[sub][2], 0, 0, 0);
            oacc[sub][3] = __builtin_amdgcn_mfma_f32_16x16x32_f16(cv3, bp[sub], oacc[sub][3], 0, 0, 0);
        }
        // phase 4: cv registers dead -> prefetch next chunk's V (covered by next QK+exp)
        cv0 = *(const f16x8*)(nvb);
        cv1 = *(const f16x8*)(nvb + 1024);
        cv2 = *(const f16x8*)(nvb + 2048);
        cv3 = *(const f16x8*)(nvb + 3072);
    }

    // ---- combine the 4 kw waves (sequential rounds, one small LDS buffer) ----
    __shared__ float comb[64][69];          // stride 69: gcd(69,32)=1, conflict-free
    for (int r = 1; r < 4; ++r) {
        if (kw == r) dump_part(comb, lane, oacc, lacc);
        __syncthreads();
        if (kw == 0) add_part(comb, lane, oacc, lacc);
        __syncthreads();
    }

    if (kw == 0) {
        // lacc[s][0] is the full denominator for column q = l15 (MFMA reduced all k in-instruction)
#pragma unroll
        for (int sub = 0; sub < 4; ++sub) {
            const int qrow = qt * 64 + sub * 16 + l15;
            if (qrow < NTOK) {
                const float inv = 1.0f / lacc[sub][0];
#pragma unroll
                for (int db = 0; db < 4; ++db)
#pragma unroll
                    for (int q = 0; q < 4; ++q) {
                        const int d = db * 16 + 4 * grp + q;   // O^T: row=d, col=q
                        out[((size_t)b * NCH + (size_t)d * NHEADS + head) * NTOK + qrow] = oacc[sub][db][q] * inv;
                    }
            }
        }
    }
}

extern "C" void kernel_launch(void* const* d_in, const int* in_sizes, int n_in,
                              void* d_out, int out_size, void* d_ws, size_t ws_size,
                              hipStream_t stream)
{
    const float* x = (const float*)d_in[0];
    float* out     = (float*)d_out;

    char* Kimg = (char*)d_ws;                       // 32 * 208KB = 6.8 MB
    char* Vimg = (char*)d_ws + 32 * IMG_BH;         // + 6.8 MB

    dim3 pgrid(32, NC32);                           // 32 bh x 52 chunks
    prep_kernel<<<pgrid, 256, 0, stream>>>(x, Kimg, Vimg);

    attn_fwd<<<800, 256, 0, stream>>>(Kimg, Vimg, out);   // 25 q-tiles x 32 bh, XCD-remapped
}

// Round 13
// 42.513 us; speedup vs baseline: 6.0157x; 1.1143x over previous
//
#include <hip/hip_runtime.h>

typedef _Float16 f16x8 __attribute__((ext_vector_type(8)));
typedef _Float16 f16x4 __attribute__((ext_vector_type(4)));
typedef float    f32x4 __attribute__((ext_vector_type(4)));
typedef unsigned int u32x4 __attribute__((ext_vector_type(4)));

constexpr int NTOK   = 1568;       // T*H*W = 8*14*14
constexpr int NHEADS = 8;
constexpr int NCH    = 512;
constexpr int NC32   = 52;         // 32-token chunks, padded to 1664 tokens
constexpr float SK   = 0.15014030f; // 0.125*sqrt(log2 e): (q*SK)·(k*SK) = s*log2e/64 -> p = exp2(.)
constexpr size_t IMG_BH = (size_t)NC32 * 4096;   // 212992 B per (bh) per image

// ---- pre-pass: build fragment-major K and V images (every frag = contiguous 1KB, lane*16) ----
// K frag (c16 = tok/16, ks): slot(l15,grp,j) = x[tok=c16*16+l15][d=ks*32+8grp+j] * SK
// V frag (c32 = tok/32, db): slot(l15,grp,j) = x[tok=c32*32+16*(j>>2)+4grp+(j&3)][d=db*16+l15]
__global__ __launch_bounds__(256)
void prep_kernel(const float* __restrict__ x, char* __restrict__ Kimg, char* __restrict__ Vimg)
{
    const int bh = blockIdx.x, c32 = blockIdx.y;
    const int b = bh >> 3, h = bh & 7;
    const int t = threadIdx.x;
    const int f = t >> 6, l = t & 63, l15 = l & 15, grp = l >> 4;

    char* Kg = Kimg + (size_t)bh * IMG_BH + (size_t)(c32 * 4 + f) * 1024 + l * 16;
    char* Vg = Vimg + (size_t)bh * IMG_BH + (size_t)(c32 * 4 + f) * 1024 + l * 16;

    const int n0 = c32 * 32;
    if (n0 >= NTOK) {                       // pure padding chunk
        f16x8 z;
#pragma unroll
        for (int j = 0; j < 8; ++j) z[j] = (_Float16)0.f;
        *(f16x8*)Kg = z; *(f16x8*)Vg = z;
        return;
    }

    __shared__ _Float16 kbuf[32][72];       // [tok][d], scaled
    __shared__ _Float16 vbuf[64][40];       // [d][tok]

    const int tok = t & 31, dhi = t >> 5;   // coalesced: 8 x 128B segments per pass
#pragma unroll
    for (int p = 0; p < 8; ++p) {
        const int d = 8 * p + dhi;
        const float v = x[((size_t)b * NCH + d * NHEADS + h) * NTOK + n0 + tok];
        kbuf[tok][d] = (_Float16)(v * SK);
        vbuf[d][tok] = (_Float16)v;
    }
    __syncthreads();

    // K frag f: cb = f>>1 (16-tok half), ks = f&1
    *(f16x8*)Kg = *(const f16x8*)&kbuf[(f >> 1) * 16 + l15][(f & 1) * 32 + grp * 8];
    // V frag db = f: token quads {4grp..+3} and {16+4grp..+3}
    f16x4 va = *(const f16x4*)&vbuf[f * 16 + l15][4 * grp];
    f16x4 vb = *(const f16x4*)&vbuf[f * 16 + l15][16 + 4 * grp];
    f16x8 vv;
#pragma unroll
    for (int j = 0; j < 4; ++j) { vv[j] = va[j]; vv[4 + j] = vb[j]; }
    *(f16x8*)Vg = vv;
}

// pack 8 exp2(s) values into one P fragment — pure register ops, no union/memory
static __device__ __forceinline__ f16x8 make_bp(f32x4 sA, f32x4 sB)
{
    u32x4 w;
    w[0] = __builtin_bit_cast(unsigned int,
        __builtin_amdgcn_cvt_pkrtz(__builtin_amdgcn_exp2f(sA[0]), __builtin_amdgcn_exp2f(sA[1])));
    w[1] = __builtin_bit_cast(unsigned int,
        __builtin_amdgcn_cvt_pkrtz(__builtin_amdgcn_exp2f(sA[2]), __builtin_amdgcn_exp2f(sA[3])));
    w[2] = __builtin_bit_cast(unsigned int,
        __builtin_amdgcn_cvt_pkrtz(__builtin_amdgcn_exp2f(sB[0]), __builtin_amdgcn_exp2f(sB[1])));
    w[3] = __builtin_bit_cast(unsigned int,
        __builtin_amdgcn_cvt_pkrtz(__builtin_amdgcn_exp2f(sB[2]), __builtin_amdgcn_exp2f(sB[3])));
    return __builtin_bit_cast(f16x8, w);
}

// combine helpers: statically-indexed register arrays by reference (inlined -> stays in VGPRs)
static __device__ __forceinline__ void dump_part(float (*row)[35], int lane,
                                                 const f32x4 (&oacc)[2][4], const f32x4 (&lacc)[2])
{
#pragma unroll
    for (int s = 0; s < 2; ++s) {
#pragma unroll
        for (int db = 0; db < 4; ++db)
#pragma unroll
            for (int q = 0; q < 4; ++q) row[lane][s * 16 + db * 4 + q] = oacc[s][db][q];
        row[lane][32 + s] = lacc[s][0];
    }
}
static __device__ __forceinline__ void add_part(const float (*row)[35], int lane,
                                                f32x4 (&oacc)[2][4], f32x4 (&lacc)[2])
{
#pragma unroll
    for (int s = 0; s < 2; ++s) {
#pragma unroll
        for (int db = 0; db < 4; ++db)
#pragma unroll
            for (int q = 0; q < 4; ++q) oacc[s][db][q] += row[lane][s * 16 + db * 4 + q];
        lacc[s][0] += row[lane][32 + s];
    }
}

// ---- main attention: QBLK=32 (2 subs/wave), 4 waves k-split, no LDS/barriers in hot loop ----
// Register budget ~110 total (arch+acc) -> 4 waves/SIMD; grid 1568 blocks = 6272 waves.
// Loop body deliberately unconstrained (round-9 form): compiler hoists next-chunk loads.
__global__ __launch_bounds__(256, 4)
void attn_fwd(const char* __restrict__ Kimg, const char* __restrict__ Vimg,
              float* __restrict__ out)
{
    // XCD-aware bijective remap (1568 = 8*196): 4 bh per XCD -> both images L2-resident
    const int orig = blockIdx.x;
    const int wgid = (orig & 7) * 196 + (orig >> 3);
    const int qt = wgid % 49, bh = wgid / 49;       // qt: 32-row q-tile, 49*32 = 1568 exactly
    const int b = bh >> 3, head = bh & 7;
    const int t = threadIdx.x, kw = t >> 6, lane = t & 63;
    const int l15 = lane & 15, grp = lane >> 4;

    const char* Kb = Kimg + (size_t)bh * IMG_BH;
    const char* Vb = Vimg + (size_t)bh * IMG_BH;

    // Q fragments: B operand (col = l15 = q-row), from the padded K image (scale baked in)
    f16x8 aq[2][2];
#pragma unroll
    for (int sub = 0; sub < 2; ++sub)
#pragma unroll
        for (int ks = 0; ks < 2; ++ks)
            aq[sub][ks] = *(const f16x8*)(Kb + (size_t)((qt * 2 + sub) * 2 + ks) * 1024 + lane * 16);

    f16x8 ones;
#pragma unroll
    for (int j = 0; j < 8; ++j) ones[j] = (_Float16)1.f;

    f32x4 oacc[2][4];
    f32x4 lacc[2];
#pragma unroll
    for (int s = 0; s < 2; ++s) {
        lacc[s] = f32x4{0.f, 0.f, 0.f, 0.f};
#pragma unroll
        for (int db = 0; db < 4; ++db) oacc[s][db] = f32x4{0.f, 0.f, 0.f, 0.f};
    }

    // 49 valid chunks split 13/12/12/12 across the 4 kw waves
    const int start = (kw == 0) ? 0 : 13 + (kw - 1) * 12;
    const int nc    = (kw == 0) ? 13 : 12;
    const f32x4 z4 = {0.f, 0.f, 0.f, 0.f};

    for (int i = 0; i < nc; ++i) {
        const int c32 = start + i;
        const char* kbase = Kb + (size_t)c32 * 4096 + lane * 16;
        const char* vbase = Vb + (size_t)c32 * 4096 + lane * 16;

        f16x8 ka0 = *(const f16x8*)(kbase);
        f16x8 ka1 = *(const f16x8*)(kbase + 1024);
        f16x8 kb0 = *(const f16x8*)(kbase + 2048);
        f16x8 kb1 = *(const f16x8*)(kbase + 3072);
        f16x8 vf0 = *(const f16x8*)(vbase);
        f16x8 vf1 = *(const f16x8*)(vbase + 1024);
        f16x8 vf2 = *(const f16x8*)(vbase + 2048);
        f16x8 vf3 = *(const f16x8*)(vbase + 3072);

        // per q-subgroup: S^T both 16-token halves -> pack P -> denominator + PV MFMAs
#pragma unroll
        for (int sub = 0; sub < 2; ++sub) {
            f32x4 sA = __builtin_amdgcn_mfma_f32_16x16x32_f16(ka0, aq[sub][0], z4, 0, 0, 0);
            sA = __builtin_amdgcn_mfma_f32_16x16x32_f16(ka1, aq[sub][1], sA, 0, 0, 0);
            f32x4 sB = __builtin_amdgcn_mfma_f32_16x16x32_f16(kb0, aq[sub][0], z4, 0, 0, 0);
            sB = __builtin_amdgcn_mfma_f32_16x16x32_f16(kb1, aq[sub][1], sB, 0, 0, 0);
            const f16x8 bp = make_bp(sA, sB);   // slot j = token 16*(j>>2)+4grp+(j&3)
            lacc[sub]    = __builtin_amdgcn_mfma_f32_16x16x32_f16(ones, bp, lacc[sub], 0, 0, 0);
            oacc[sub][0] = __builtin_amdgcn_mfma_f32_16x16x32_f16(vf0, bp, oacc[sub][0], 0, 0, 0);
            oacc[sub][1] = __builtin_amdgcn_mfma_f32_16x16x32_f16(vf1, bp, oacc[sub][1], 0, 0, 0);
            oacc[sub][2] = __builtin_amdgcn_mfma_f32_16x16x32_f16(vf2, bp, oacc[sub][2], 0, 0, 0);
            oacc[sub][3] = __builtin_amdgcn_mfma_f32_16x16x32_f16(vf3, bp, oacc[sub][3], 0, 0, 0);
        }
    }

    // ---- combine the 4 kw waves (sequential rounds, one small LDS buffer) ----
    __shared__ float comb[64][35];          // stride 35 (odd): worst 2-way banks = free
    for (int r = 1; r < 4; ++r) {
        if (kw == r) dump_part(comb, lane, oacc, lacc);
        __syncthreads();
        if (kw == 0) add_part(comb, lane, oacc, lacc);
        __syncthreads();
    }

    if (kw == 0) {
        // lacc[s][0] is the full denominator for column q = l15 (MFMA reduced all k in-instruction)
#pragma unroll
        for (int sub = 0; sub < 2; ++sub) {
            const int qrow = qt * 32 + sub * 16 + l15;      // always < 1568
            const float inv = 1.0f / lacc[sub][0];
#pragma unroll
            for (int db = 0; db < 4; ++db)
#pragma unroll
                for (int q = 0; q < 4; ++q) {
                    const int d = db * 16 + 4 * grp + q;    // O^T: row=d, col=q
                    out[((size_t)b * NCH + (size_t)d * NHEADS + head) * NTOK + qrow] = oacc[sub][db][q] * inv;
                }
        }
    }
}

extern "C" void kernel_launch(void* const* d_in, const int* in_sizes, int n_in,
                              void* d_out, int out_size, void* d_ws, size_t ws_size,
                              hipStream_t stream)
{
    const float* x = (const float*)d_in[0];
    float* out     = (float*)d_out;

    char* Kimg = (char*)d_ws;                       // 32 * 208KB = 6.8 MB
    char* Vimg = (char*)d_ws + 32 * IMG_BH;         // + 6.8 MB

    dim3 pgrid(32, NC32);                           // 32 bh x 52 chunks
    prep_kernel<<<pgrid, 256, 0, stream>>>(x, Kimg, Vimg);

    attn_fwd<<<1568, 256, 0, stream>>>(Kimg, Vimg, out);   // 49 q-tiles x 32 bh, XCD-remapped
}